// Round 3
// baseline (329.618 us; speedup 1.0000x reference)
//
#include <hip/hip_runtime.h>
#include <stdint.h>

typedef _Float16 f16;
typedef _Float16 f16x2 __attribute__((ext_vector_type(2)));
typedef _Float16 f16x4 __attribute__((ext_vector_type(4)));
typedef _Float16 f16x8 __attribute__((ext_vector_type(8)));
typedef float f32x4 __attribute__((ext_vector_type(4)));

typedef __attribute__((address_space(1))) void gvoid;
typedef __attribute__((address_space(3))) void lvoid;

#define NROWS 4096
#define DIMIN 1536
#define DMLP 512
#define FDIM 256
#define NCLS 10000
#define NPAD 10112   // 79 * 128

__device__ __forceinline__ void load_lds16(const void* g, void* l) {
    __builtin_amdgcn_global_load_lds((gvoid*)g, (lvoid*)l, 16, 0, 0);
}

// ---------------------------------------------------------------------------
// fp16 GEMM: C[M,N] = A[M,K] @ Bt[N,K]^T (+bias). 256 thr = 4 waves (2x2),
// BK=64, XOR-swizzled LDS (swizzle applied to GLOBAL source; LDS linear).
// ---------------------------------------------------------------------------
template<int TM, int TN>
__global__ __launch_bounds__(256) void gemm_t(
    const f16* __restrict__ A, const f16* __restrict__ Bt,
    float* __restrict__ C, const float* __restrict__ bias,
    int K, int ldc, int Nstore)
{
    constexpr int BK = 64;
    constexpr int AM = TM / 32;
    constexpr int AN = TN / 32;
    constexpr int CA = TM * 8;
    constexpr int CB = TN * 8;
    constexpr int RTOT = (CA + CB) / 256;

    __shared__ f16 As[TM * BK];
    __shared__ f16 Bs[TN * BK];

    const int tid  = threadIdx.x;
    const int lane = tid & 63;
    const int w    = tid >> 6;
    const int wm   = (w >> 1) * (TM / 2);
    const int wn   = (w & 1) * (TN / 2);
    const int row0 = blockIdx.x * TM;
    const int col0 = blockIdx.y * TN;
    const int quad = lane >> 4;
    const int r16  = lane & 15;

    f32x4 acc[AM][AN] = {};

    const f16* gsrc[RTOT];
    f16* ldst[RTOT];
#pragma unroll
    for (int r = 0; r < RTOT; ++r) {
        int c = tid + r * 256;
        bool isA = (c < CA);
        int cc = isA ? c : c - CA;
        int row = cc >> 3;
        int gs = (cc & 7) ^ (row & 7);
        gsrc[r] = (isA ? A + (size_t)(row0 + row) * K
                       : Bt + (size_t)(col0 + row) * K) + gs * 8;
        ldst[r] = (isA ? As : Bs) + cc * 8;
    }

    for (int k0 = 0; k0 < K; k0 += BK) {
#pragma unroll
        for (int r = 0; r < RTOT; ++r)
            load_lds16(gsrc[r] + k0, ldst[r]);
        __syncthreads();

#pragma unroll
        for (int ks = 0; ks < 2; ++ks) {
            const int slot = (ks * 4 + quad) ^ (r16 & 7);
            f16x8 af[AM], bq[AN];
#pragma unroll
            for (int mi = 0; mi < AM; ++mi)
                af[mi] = *(const f16x8*)&As[(wm + mi * 16 + r16) * BK + slot * 8];
#pragma unroll
            for (int ni = 0; ni < AN; ++ni)
                bq[ni] = *(const f16x8*)&Bs[(wn + ni * 16 + r16) * BK + slot * 8];
#pragma unroll
            for (int mi = 0; mi < AM; ++mi)
#pragma unroll
                for (int ni = 0; ni < AN; ++ni)
                    acc[mi][ni] = __builtin_amdgcn_mfma_f32_16x16x32_f16(
                        af[mi], bq[ni], acc[mi][ni], 0, 0, 0);
        }
        __syncthreads();
    }

    // C/D layout: col = lane&15, row = quad*4 + reg
#pragma unroll
    for (int mi = 0; mi < AM; ++mi) {
#pragma unroll
        for (int ni = 0; ni < AN; ++ni) {
            int col = col0 + wn + ni * 16 + r16;
            if (col < Nstore) {
                float bv = bias ? bias[col] : 0.0f;
                int rowb = row0 + wm + mi * 16 + quad * 4;
#pragma unroll
                for (int r = 0; r < 4; ++r)
                    C[(size_t)(rowb + r) * ldc + col] = acc[mi][ni][r] + bv;
            }
        }
    }
}

// ---------------------------------------------------------------------------
// GEMM2 + bias + row L2-norm fused: A=h2[4096,512], Bt=W2t[256,512].
// TM=32 rows/block, TN=256 = full feature dim -> whole row in-block.
// ---------------------------------------------------------------------------
__global__ __launch_bounds__(256) void gemm2_l2_k(
    const f16* __restrict__ A, const f16* __restrict__ Bt,
    const float* __restrict__ bias,
    float* __restrict__ feat, f16* __restrict__ feath)
{
    constexpr int TM = 32, TN = 256, BK = 64, K = 512;
    constexpr int AN = 8;                 // wave tile 16 x 128
    constexpr int CA = TM * 8;            // 256
    constexpr int CB = TN * 8;            // 2048
    constexpr int RTOT = (CA + CB) / 256; // 9

    __shared__ f16 As[TM * BK];           // 4 KB
    __shared__ f16 Bs[TN * BK];           // 32 KB
    __shared__ float part[2][TM];

    const int tid = threadIdx.x, lane = tid & 63, w = tid >> 6;
    const int wm = (w >> 1) * 16;
    const int wh = (w & 1);
    const int wn = wh * 128;
    const int row0 = blockIdx.x * TM;
    const int quad = lane >> 4, r16 = lane & 15;

    f32x4 acc[AN] = {};

    const f16* gsrc[RTOT];
    f16* ldst[RTOT];
#pragma unroll
    for (int r = 0; r < RTOT; ++r) {
        int c = tid + r * 256;
        bool isA = (c < CA);
        int cc = isA ? c : c - CA;
        int row = cc >> 3;
        int gs = (cc & 7) ^ (row & 7);
        gsrc[r] = (isA ? A + (size_t)(row0 + row) * K
                       : Bt + (size_t)row * K) + gs * 8;
        ldst[r] = (isA ? As : Bs) + cc * 8;
    }

    for (int k0 = 0; k0 < K; k0 += BK) {
#pragma unroll
        for (int r = 0; r < RTOT; ++r)
            load_lds16(gsrc[r] + k0, ldst[r]);
        __syncthreads();
#pragma unroll
        for (int ks = 0; ks < 2; ++ks) {
            const int slot = (ks * 4 + quad) ^ (r16 & 7);
            f16x8 af = *(const f16x8*)&As[(wm + r16) * BK + slot * 8];
#pragma unroll
            for (int ni = 0; ni < AN; ++ni) {
                f16x8 bq = *(const f16x8*)&Bs[(wn + ni * 16 + r16) * BK + slot * 8];
                acc[ni] = __builtin_amdgcn_mfma_f32_16x16x32_f16(af, bq, acc[ni], 0, 0, 0);
            }
        }
        __syncthreads();
    }

    // bias + per-row sumsq; lane covers rows wm+quad*4+r, cols wn+16ni+r16
    float s[4] = {0.f, 0.f, 0.f, 0.f};
#pragma unroll
    for (int ni = 0; ni < AN; ++ni) {
        float b = bias[wn + ni * 16 + r16];
#pragma unroll
        for (int r = 0; r < 4; ++r) {
            acc[ni][r] += b;
            s[r] += acc[ni][r] * acc[ni][r];
        }
    }
#pragma unroll
    for (int off = 1; off < 16; off <<= 1)
#pragma unroll
        for (int r = 0; r < 4; ++r)
            s[r] += __shfl_xor(s[r], off);
    if (r16 == 0)
#pragma unroll
        for (int r = 0; r < 4; ++r)
            part[wh][wm + quad * 4 + r] = s[r];
    __syncthreads();

    float inv[4];
#pragma unroll
    for (int r = 0; r < 4; ++r) {
        int row = wm + quad * 4 + r;
        float tot = part[0][row] + part[1][row];
        inv[r] = 1.0f / fmaxf(sqrtf(tot), 1e-12f);
    }
#pragma unroll
    for (int ni = 0; ni < AN; ++ni) {
        int col = wn + ni * 16 + r16;
#pragma unroll
        for (int r = 0; r < 4; ++r) {
            int row = row0 + wm + quad * 4 + r;
            float v = acc[ni][r] * inv[r];
            feat[(size_t)row * FDIM + col] = v;
            feath[(size_t)row * FDIM + col] = (f16)v;
        }
    }
}

// ---------------------------------------------------------------------------
// prep: zero BN stats + feat_in->f16 + W1^T->f16 + W2^T->f16, one launch
__global__ void prep_k(const float* __restrict__ feat_in, const float* __restrict__ W1,
                       const float* __restrict__ W2, f16* __restrict__ A1h,
                       f16* __restrict__ W1t, f16* __restrict__ W2t,
                       float* __restrict__ stats) {
    int idx = blockIdx.x * 256 + threadIdx.x;
    if (idx < 1024) { stats[idx] = 0.0f; return; }
    idx -= 1024;
    if (idx < NROWS * DIMIN / 4) {
        float4 v = *(const float4*)&feat_in[(size_t)idx * 4];
        f16x4 o = {(f16)v.x, (f16)v.y, (f16)v.z, (f16)v.w};
        *(f16x4*)&A1h[(size_t)idx * 4] = o;
        return;
    }
    idx -= NROWS * DIMIN / 4;
    if (idx < DMLP * DIMIN) {
        int n = idx / DIMIN, k = idx - n * DIMIN;
        W1t[idx] = (f16)W1[(size_t)k * DMLP + n];
        return;
    }
    idx -= DMLP * DIMIN;
    if (idx < FDIM * DMLP) {
        int n = idx / DMLP, k = idx - n * DMLP;
        W2t[idx] = (f16)W2[(size_t)k * FDIM + n];
    }
}

// column sums/sumsq of h [4096,512]
__global__ void bn_stats_k(const float* __restrict__ h, float* __restrict__ sums, float* __restrict__ sqs) {
    int t = threadIdx.x, b = blockIdx.x;
    int c = t * 2;
    float s0 = 0.f, s1 = 0.f, q0 = 0.f, q1 = 0.f;
    for (int r = b; r < NROWS; r += 128) {
        float2 v = *(const float2*)&h[(size_t)r * DMLP + c];
        s0 += v.x; s1 += v.y; q0 += v.x * v.x; q1 += v.y * v.y;
    }
    atomicAdd(&sums[c], s0);
    atomicAdd(&sums[c + 1], s1);
    atomicAdd(&sqs[c], q0);
    atomicAdd(&sqs[c + 1], q1);
}

// BN apply (stats folded inline) + ReLU + cast to fp16; float4 per thread
__global__ void bn_apply_k(const float* __restrict__ h, const float* __restrict__ sums,
                           const float* __restrict__ sqs, const float* __restrict__ gamma,
                           const float* __restrict__ beta, f16* __restrict__ out) {
    int i = blockIdx.x * 256 + threadIdx.x;     // over 4096*512/4
    int c = (i & 127) * 4;
    float4 v  = *(const float4*)&h[(size_t)i * 4];
    float4 sm = *(const float4*)&sums[c];
    float4 sq = *(const float4*)&sqs[c];
    float4 gm = *(const float4*)&gamma[c];
    float4 bt = *(const float4*)&beta[c];
    const float inv_n = 1.0f / 4096.0f;
    float mu, var, a;
    mu = sm.x * inv_n; var = fmaxf(sq.x * inv_n - mu * mu, 0.f); a = rsqrtf(var + 1e-5f) * gm.x;
    float o0 = fmaxf((v.x - mu) * a + bt.x, 0.f);
    mu = sm.y * inv_n; var = fmaxf(sq.y * inv_n - mu * mu, 0.f); a = rsqrtf(var + 1e-5f) * gm.y;
    float o1 = fmaxf((v.y - mu) * a + bt.y, 0.f);
    mu = sm.z * inv_n; var = fmaxf(sq.z * inv_n - mu * mu, 0.f); a = rsqrtf(var + 1e-5f) * gm.z;
    float o2 = fmaxf((v.z - mu) * a + bt.z, 0.f);
    mu = sm.w * inv_n; var = fmaxf(sq.w * inv_n - mu * mu, 0.f); a = rsqrtf(var + 1e-5f) * gm.w;
    float o3 = fmaxf((v.w - mu) * a + bt.w, 0.f);
    f16x4 o = {(f16)o0, (f16)o1, (f16)o2, (f16)o3};
    *(f16x4*)&out[(size_t)i * 4] = o;
}

// per-label sequential momentum chain + f16 memory-bank materialization
__global__ void chain_k(const int* __restrict__ label, const float* __restrict__ feat,
                        const float* __restrict__ mp, f16* __restrict__ memh) {
    int y = (blockIdx.x * 256 + threadIdx.x) >> 6;
    int lane = threadIdx.x & 63;
    float4 m = {0.f, 0.f, 0.f, 0.f};
    if (y < NCLS) {
        m = *(const float4*)&mp[(size_t)y * FDIM + lane * 4];
        for (int g = 0; g < 64; ++g) {
            int lab = label[g * 64 + lane];
            unsigned long long mask = __ballot(lab == y);
            while (mask) {
                int b = __builtin_ctzll(mask);
                mask &= mask - 1;
                int i = g * 64 + b;
                float4 x = *(const float4*)&feat[(size_t)i * FDIM + lane * 4];
                m.x = 0.9f * m.x + 0.1f * x.x;
                m.y = 0.9f * m.y + 0.1f * x.y;
                m.z = 0.9f * m.z + 0.1f * x.z;
                m.w = 0.9f * m.w + 0.1f * x.w;
                float s = m.x * m.x + m.y * m.y + m.z * m.z + m.w * m.w;
#pragma unroll
                for (int off = 32; off > 0; off >>= 1) s += __shfl_xor(s, off);
                float inv = 1.0f / fmaxf(sqrtf(s), 1e-12f);
                m.x *= inv; m.y *= inv; m.z *= inv; m.w *= inv;
            }
        }
    }
    f16x4 o = {(f16)m.x, (f16)m.y, (f16)m.z, (f16)m.w};
    *(f16x4*)&memh[(size_t)y * FDIM + lane * 4] = o;
}

// ---------------------------------------------------------------------------
extern "C" void kernel_launch(void* const* d_in, const int* in_sizes, int n_in,
                              void* d_out, int out_size, void* d_ws, size_t ws_size,
                              hipStream_t stream) {
    const float* feat_in = (const float*)d_in[0];
    const int*   label   = (const int*)d_in[1];
    const float* W1      = (const float*)d_in[2];
    const float* b1      = (const float*)d_in[3];
    const float* gamma   = (const float*)d_in[4];
    const float* beta    = (const float*)d_in[5];
    const float* W2      = (const float*)d_in[6];
    const float* b2      = (const float*)d_in[7];
    const float* mp      = (const float*)d_in[8];
    float* out = (float*)d_out;

    char* w = (char*)d_ws;
    f16* A1h   = (f16*)w;   w += (size_t)NROWS * DIMIN * 2;
    f16* W1t   = (f16*)w;   w += (size_t)DMLP * DIMIN * 2;
    f16* W2t   = (f16*)w;   w += (size_t)FDIM * DMLP * 2;
    float* h   = (float*)w; w += (size_t)NROWS * DMLP * 4;
    f16* h2    = (f16*)w;   w += (size_t)NROWS * DMLP * 2;
    float* feat= (float*)w; w += (size_t)NROWS * FDIM * 4;
    f16* feath = (f16*)w;   w += (size_t)NROWS * FDIM * 2;
    f16* memh  = (f16*)w;   w += (size_t)NPAD * FDIM * 2;
    float* sums= (float*)w; w += DMLP * 4;
    float* sqs = (float*)w; w += DMLP * 4;

    // 1) prep: zero stats + convert A + transpose W1,W2  (9732 blocks)
    prep_k<<<(1024 + NROWS * DIMIN / 4 + DMLP * DIMIN + FDIM * DMLP) / 256, 256, 0, stream>>>(
        feat_in, W1, W2, A1h, W1t, W2t, sums);

    // 2) GEMM1: h = feat_in @ W1 + b1   (512 blocks)
    {
        dim3 g(NROWS / 64, DMLP / 64);
        gemm_t<64, 64><<<g, 256, 0, stream>>>(A1h, W1t, h, b1, DIMIN, DMLP, DMLP);
    }

    // 3) BN stats
    bn_stats_k<<<128, 256, 0, stream>>>(h, sums, sqs);

    // 4) BN apply + ReLU + cast
    bn_apply_k<<<(NROWS * DMLP / 4) / 256, 256, 0, stream>>>(h, sums, sqs, gamma, beta, h2);

    // 5) GEMM2 + bias + l2norm fused -> feat fp32 + feath f16  (128 blocks)
    gemm2_l2_k<<<NROWS / 32, 256, 0, stream>>>(h2, W2t, b2, feat, feath);

    // 6) memory bank chains + f16 materialization
    chain_k<<<NPAD / 4, 256, 0, stream>>>(label, feat, mp, memh);

    // 7) GEMM3: sim = feat @ mem^T  (256x128 tiles -> 1264 blocks)
    {
        dim3 g(NROWS / 256, NPAD / 128);
        gemm_t<256, 128><<<g, 256, 0, stream>>>(feath, memh, out, nullptr, FDIM, NCLS, NCLS);
    }
}